// Round 4
// baseline (9193.400 us; speedup 1.0000x reference)
//
#include <hip/hip_runtime.h>

#define BATCH 64
#define NH 224          // rows of img2d (and eigen dimension)
#define NCW 672         // cols of img2d
#define CSTRIDE 256     // padded column stride for G (224 data + 32 zero pad)
#define KKEEP 179       // int(0.8*224)
#define NTAIL 45        // 224 - 179
#define NSWEEPS 10
#define EPS2 1e-18f

__device__ __forceinline__ float fast_rcp(float x) { return __builtin_amdgcn_rcpf(x); }
__device__ __forceinline__ float fast_rsq(float x) { return __builtin_amdgcn_rsqf(x); }
__device__ __forceinline__ float fast_sqrt(float x) { return __builtin_amdgcn_sqrtf(x); }

// Intra-block disjoint pair schedule: 7 mini-rounds x 3 pairs, i+j == t (mod 7)
__device__ __constant__ const int IP[7][3][2] = {
    {{1, 6}, {2, 5}, {3, 4}},
    {{0, 1}, {2, 6}, {3, 5}},
    {{0, 2}, {3, 6}, {4, 5}},
    {{0, 3}, {1, 2}, {4, 6}},
    {{0, 4}, {1, 3}, {5, 6}},
    {{0, 5}, {1, 4}, {2, 3}},
    {{0, 6}, {1, 5}, {2, 4}}};

// ---------------------------------------------------------------- p_obs
__global__ __launch_bounds__(256) void pobs_kernel(const int* __restrict__ mask,
                                                   float* __restrict__ invp) {
    int b = blockIdx.x, tid = threadIdx.x;
    const int* mb = mask + (size_t)b * NH * NCW;
    int s = 0;
    for (int i = tid; i < NH * NCW; i += 256) s += mb[i];
    __shared__ int red[256];
    red[tid] = s;
    __syncthreads();
    for (int o = 128; o; o >>= 1) {
        if (tid < o) red[tid] += red[tid + o];
        __syncthreads();
    }
    if (tid == 0) invp[b] = (float)(NH * NCW) / (float)red[0];
}

// ------------------------------------------------- zero the pad rows of G
__global__ void pad_kernel(float* __restrict__ G) {
    int idx = blockIdx.x * 256 + threadIdx.x;  // BATCH*224*32 total
    int b = idx / (NH * 32);
    int rem = idx - b * (NH * 32);
    int j = rem >> 5;
    int i = NH + (rem & 31);
    G[((size_t)b * NH + j) * CSTRIDE + i] = 0.f;
}

// ------------------------------------------------------- G = A * A^T
__global__ __launch_bounds__(256) void gram_kernel(const float* __restrict__ x,
                                                   const int* __restrict__ mask,
                                                   float* __restrict__ G) {
    int b = blockIdx.y;
    int tile = blockIdx.x;       // 0..48
    int ti = tile / 7, tj = tile - ti * 7;
    int i0 = ti * 32, j0 = tj * 32;
    __shared__ float As[32][33];
    __shared__ float Bs[32][33];
    int tid = threadIdx.x;
    int tx = tid & 31;
    int ty = tid >> 5;
    float acc0 = 0, acc1 = 0, acc2 = 0, acc3 = 0;
    const float* xb = x + (size_t)b * 3 * NH * NH;
    const int* mb = mask + (size_t)b * NH * NCW;
    for (int ks = 0; ks < 21; ++ks) {
        int k0 = ks * 32;
        int c = k0 / NH;
        int w0 = k0 - c * NH;
        __syncthreads();
        for (int l = tid; l < 1024; l += 256) {
            int dk = l & 31, di = l >> 5;
            int hA = i0 + di, hB = j0 + di;
            float xa = xb[(c * NH + hA) * NH + w0 + dk];
            float xc = xb[(c * NH + hB) * NH + w0 + dk];
            As[di][dk] = mb[hA * NCW + k0 + dk] ? 2.f * xa - 1.f : 0.f;
            Bs[di][dk] = mb[hB * NCW + k0 + dk] ? 2.f * xc - 1.f : 0.f;
        }
        __syncthreads();
#pragma unroll
        for (int kk = 0; kk < 32; ++kk) {
            float bv = Bs[tx][kk];
            acc0 += As[ty][kk] * bv;
            acc1 += As[ty + 8][kk] * bv;
            acc2 += As[ty + 16][kk] * bv;
            acc3 += As[ty + 24][kk] * bv;
        }
    }
    float* Gb = G + (size_t)b * NH * CSTRIDE;
    int j = j0 + tx;
    Gb[j * CSTRIDE + i0 + ty] = acc0;
    Gb[j * CSTRIDE + i0 + ty + 8] = acc1;
    Gb[j * CSTRIDE + i0 + ty + 16] = acc2;
    Gb[j * CSTRIDE + i0 + ty + 24] = acc3;
}

// ---------------------------------------------- blocked one-sided Jacobi
// 32 blocks x 7 columns; tournament over block pairs, one wave per pair.
// Rotations inside a round are grouped into mini-rounds of DISJOINT pairs so
// the 6-level shuffle reductions interleave (amortize ~120cyc ds-op latency).
__global__ __launch_bounds__(1024, 4) void jacobi_kernel(float* __restrict__ G) {
    int b = blockIdx.x;
    float* Gb = G + (size_t)b * NH * CSTRIDE;
    __shared__ float lam[NH];
    int tid = threadIdx.x, lane = tid & 63, wid = tid >> 6;  // 16 waves
    for (int k = 0; k < 14; ++k) {
        int j = wid * 14 + k;
        float4 v = ((const float4*)(Gb + j * CSTRIDE))[lane];
        float d = v.x * v.x + v.y * v.y + v.z * v.z + v.w * v.w;
        d += __shfl_xor(d, 32); d += __shfl_xor(d, 16); d += __shfl_xor(d, 8);
        d += __shfl_xor(d, 4);  d += __shfl_xor(d, 2);  d += __shfl_xor(d, 1);
        if (lane == 0) lam[j] = d;
    }
    __syncthreads();
    for (int sweep = 0; sweep < NSWEEPS; ++sweep) {
        for (int r = 0; r < 31; ++r) {
            int bp, bq;
            if (wid == 0) {
                bp = 31; bq = r;
            } else {
                bp = r + wid; if (bp >= 31) bp -= 31;
                bq = r - wid; if (bq < 0) bq += 31;
            }
            int cp0 = bp * 7, cq0 = bq * 7;
            float4 c[14];
            float l[14];
#pragma unroll
            for (int k = 0; k < 7; ++k) {
                c[k]     = ((const float4*)(Gb + (cp0 + k) * CSTRIDE))[lane];
                c[7 + k] = ((const float4*)(Gb + (cq0 + k) * CSTRIDE))[lane];
                l[k]     = lam[cp0 + k];
                l[7 + k] = lam[cq0 + k];
            }
            if (r == 0) {
                // intra-block: 7 mini-rounds x 6 disjoint pairs (3 per block)
#pragma unroll
                for (int t = 0; t < 7; ++t) {
                    float apq[6], tv[6];
#pragma unroll
                    for (int k = 0; k < 6; ++k) {
                        int p = IP[t][k % 3][0] + (k < 3 ? 0 : 7);
                        int q = IP[t][k % 3][1] + (k < 3 ? 0 : 7);
                        apq[k] = c[p].x * c[q].x + c[p].y * c[q].y +
                                 c[p].z * c[q].z + c[p].w * c[q].w;
                    }
#pragma unroll
                    for (int o = 32; o; o >>= 1)
#pragma unroll
                        for (int k = 0; k < 6; ++k) apq[k] += __shfl_xor(apq[k], o);
#pragma unroll
                    for (int k = 0; k < 6; ++k) {
                        int p = IP[t][k % 3][0] + (k < 3 ? 0 : 7);
                        int q = IP[t][k % 3][1] + (k < 3 ? 0 : 7);
                        float tau = (l[q] - l[p]) * 0.5f * fast_rcp(apq[k]);
                        float tt = copysignf(
                            fast_rcp(fabsf(tau) + fast_sqrt(1.f + tau * tau)), tau);
                        bool valid = apq[k] * apq[k] > EPS2 * l[p] * l[q];
                        tv[k] = valid ? tt : 0.f;
                    }
#pragma unroll
                    for (int k = 0; k < 6; ++k) {
                        int p = IP[t][k % 3][0] + (k < 3 ? 0 : 7);
                        int q = IP[t][k % 3][1] + (k < 3 ? 0 : 7);
                        if (tv[k] != 0.f) {
                            float tt = tv[k];
                            float cc = fast_rsq(1.f + tt * tt);
                            float ss = tt * cc;
                            float4 a = c[p], bb = c[q];
                            c[p].x = cc * a.x - ss * bb.x; c[q].x = ss * a.x + cc * bb.x;
                            c[p].y = cc * a.y - ss * bb.y; c[q].y = ss * a.y + cc * bb.y;
                            c[p].z = cc * a.z - ss * bb.z; c[q].z = ss * a.z + cc * bb.z;
                            c[p].w = cc * a.w - ss * bb.w; c[q].w = ss * a.w + cc * bb.w;
                            l[p] -= tt * apq[k]; l[q] += tt * apq[k];
                        }
                    }
                }
            }
            // cross-block: 7 mini-rounds x 7 disjoint pairs
#pragma unroll
            for (int s = 0; s < 7; ++s) {
                float apq[7], tv[7];
#pragma unroll
                for (int k = 0; k < 7; ++k) {
                    int p = k, q = 7 + ((k + s) % 7);
                    apq[k] = c[p].x * c[q].x + c[p].y * c[q].y +
                             c[p].z * c[q].z + c[p].w * c[q].w;
                }
#pragma unroll
                for (int o = 32; o; o >>= 1)
#pragma unroll
                    for (int k = 0; k < 7; ++k) apq[k] += __shfl_xor(apq[k], o);
#pragma unroll
                for (int k = 0; k < 7; ++k) {
                    int p = k, q = 7 + ((k + s) % 7);
                    float tau = (l[q] - l[p]) * 0.5f * fast_rcp(apq[k]);
                    float tt = copysignf(
                        fast_rcp(fabsf(tau) + fast_sqrt(1.f + tau * tau)), tau);
                    bool valid = apq[k] * apq[k] > EPS2 * l[p] * l[q];
                    tv[k] = valid ? tt : 0.f;
                }
#pragma unroll
                for (int k = 0; k < 7; ++k) {
                    int p = k, q = 7 + ((k + s) % 7);
                    if (tv[k] != 0.f) {
                        float tt = tv[k];
                        float cc = fast_rsq(1.f + tt * tt);
                        float ss = tt * cc;
                        float4 a = c[p], bb = c[q];
                        c[p].x = cc * a.x - ss * bb.x; c[q].x = ss * a.x + cc * bb.x;
                        c[p].y = cc * a.y - ss * bb.y; c[q].y = ss * a.y + cc * bb.y;
                        c[p].z = cc * a.z - ss * bb.z; c[q].z = ss * a.z + cc * bb.z;
                        c[p].w = cc * a.w - ss * bb.w; c[q].w = ss * a.w + cc * bb.w;
                        l[p] -= tt * apq[k]; l[q] += tt * apq[k];
                    }
                }
            }
#pragma unroll
            for (int k = 0; k < 7; ++k) {
                ((float4*)(Gb + (cp0 + k) * CSTRIDE))[lane] = c[k];
                ((float4*)(Gb + (cq0 + k) * CSTRIDE))[lane] = c[7 + k];
                if (lane == 0) {
                    lam[cp0 + k] = l[k];
                    lam[cq0 + k] = l[7 + k];
                }
            }
            __syncthreads();
        }
    }
}

// --------------------------------- exact norms + select 45 smallest
__global__ __launch_bounds__(256) void select_kernel(const float* __restrict__ G,
                                                     int* __restrict__ tail_idx,
                                                     float* __restrict__ invl2) {
    int b = blockIdx.x;
    const float* Gb = G + (size_t)b * NH * CSTRIDE;
    __shared__ float lam[NH];
    __shared__ int cnt;
    int tid = threadIdx.x, lane = tid & 63, wid = tid >> 6;  // 4 waves
    if (tid == 0) cnt = 0;
    for (int j = wid * 56; j < wid * 56 + 56; ++j) {
        float4 v = ((const float4*)(Gb + j * CSTRIDE))[lane];
        float d = v.x * v.x + v.y * v.y + v.z * v.z + v.w * v.w;
        d += __shfl_xor(d, 32); d += __shfl_xor(d, 16); d += __shfl_xor(d, 8);
        d += __shfl_xor(d, 4);  d += __shfl_xor(d, 2);  d += __shfl_xor(d, 1);
        if (lane == 0) lam[j] = d;
    }
    __syncthreads();
    if (tid < NH) {
        float my = lam[tid];
        int rank = 0;
        for (int i = 0; i < NH; ++i) {
            float o = lam[i];
            rank += (o > my) ? 1 : ((o == my && i < tid) ? 1 : 0);
        }
        if (rank >= KKEEP) {
            int pos = atomicAdd(&cnt, 1);
            tail_idx[b * NTAIL + pos] = tid;
            invl2[b * NTAIL + pos] = 1.f / my;  // ||col||^2 = lambda^2
        }
    }
}

// ------------------------------- C[b][t][w'] = (col_t^T A)[w'] / lambda^2
__global__ __launch_bounds__(128) void ctail_kernel(const float* __restrict__ G,
                                                    const float* __restrict__ x,
                                                    const int* __restrict__ mask,
                                                    const int* __restrict__ tail_idx,
                                                    const float* __restrict__ invl2,
                                                    float* __restrict__ C) {
    int b = blockIdx.y;
    int wchunk = blockIdx.x;  // 6 chunks of 112
    __shared__ float sT[NTAIL * NH];
    __shared__ float sInv[NTAIL];
    __shared__ int sIdx[NTAIL];
    int tid = threadIdx.x;
    if (tid < NTAIL) {
        sIdx[tid] = tail_idx[b * NTAIL + tid];
        sInv[tid] = invl2[b * NTAIL + tid];
    }
    __syncthreads();
    for (int idx = tid; idx < NTAIL * NH; idx += 128) {
        int t = idx / NH, h = idx - t * NH;
        sT[idx] = G[((size_t)b * NH + sIdx[t]) * CSTRIDE + h];
    }
    __syncthreads();
    if (tid < 112) {
        int wp = wchunk * 112 + tid;
        int c = wp / NH;
        int w = wp - c * NH;
        const float* xb = x + ((size_t)(b * 3 + c) * NH) * NH + w;
        const int* mb = mask + (size_t)b * NH * NCW + wp;
        float acc[NTAIL];
#pragma unroll
        for (int t = 0; t < NTAIL; ++t) acc[t] = 0.f;
        for (int h = 0; h < NH; ++h) {
            float a = mb[h * NCW] ? 2.f * xb[h * NH] - 1.f : 0.f;
#pragma unroll
            for (int t = 0; t < NTAIL; ++t) acc[t] += sT[t * NH + h] * a;
        }
        float* Cb = C + ((size_t)b * NTAIL) * NCW + wp;
#pragma unroll
        for (int t = 0; t < NTAIL; ++t) Cb[t * NCW] = acc[t] * sInv[t];
    }
}

// ----------------------------------------------------------- final output
__global__ __launch_bounds__(256) void out_kernel(const float* __restrict__ G,
                                                  const float* __restrict__ x,
                                                  const int* __restrict__ mask,
                                                  const int* __restrict__ tail_idx,
                                                  const float* __restrict__ C,
                                                  const float* __restrict__ invp,
                                                  float* __restrict__ out) {
    int b = blockIdx.z, hc = blockIdx.y, wc = blockIdx.x;
    int h0 = hc * 32, w0 = wc * 96;
    __shared__ float sCol[NTAIL * 32];
    __shared__ float sC[NTAIL * 96];
    __shared__ int sIdx[NTAIL];
    int tid = threadIdx.x;
    if (tid < NTAIL) sIdx[tid] = tail_idx[b * NTAIL + tid];
    __syncthreads();
    for (int i = tid; i < NTAIL * 32; i += 256) {
        int t = i >> 5, hl = i & 31;
        sCol[i] = G[((size_t)b * NH + sIdx[t]) * CSTRIDE + h0 + hl];
    }
    for (int i = tid; i < NTAIL * 96; i += 256) {
        int t = i / 96, wl = i - t * 96;
        sC[i] = C[((size_t)b * NTAIL + t) * NCW + w0 + wl];
    }
    __syncthreads();
    float ip = invp[b];
    for (int i = tid; i < 32 * 96; i += 256) {
        int hl = i / 96, wl = i - hl * 96;
        int h = h0 + hl, wp = w0 + wl;
        int c = wp / NH, w = wp - c * NH;
        float a = mask[(size_t)b * NH * NCW + h * NCW + wp]
                      ? 2.f * x[((size_t)(b * 3 + c) * NH + h) * NH + w] - 1.f
                      : 0.f;
        float corr = 0.f;
#pragma unroll
        for (int t = 0; t < NTAIL; ++t) corr += sCol[t * 32 + hl] * sC[t * 96 + wl];
        float val = (a - corr) * ip;
        val = fminf(1.f, fmaxf(-1.f, val));
        out[((size_t)(b * 3 + c) * NH + h) * NH + w] = (val + 1.f) * 0.5f;
    }
}

extern "C" void kernel_launch(void* const* d_in, const int* in_sizes, int n_in,
                              void* d_out, int out_size, void* d_ws, size_t ws_size,
                              hipStream_t stream) {
    const float* x = (const float*)d_in[0];
    const int* mask = (const int*)d_in[1];
    float* out = (float*)d_out;
    char* ws = (char*)d_ws;

    const size_t off_G = 0;
    const size_t sz_G = (size_t)BATCH * NH * CSTRIDE * 4;
    const size_t off_invp = off_G + sz_G;
    const size_t off_tail = off_invp + 256;
    const size_t off_invl2 = off_tail + (size_t)BATCH * NTAIL * 4;
    const size_t off_C = off_invl2 + (size_t)BATCH * NTAIL * 4;

    float* G = (float*)(ws + off_G);
    float* invp = (float*)(ws + off_invp);
    int* tail = (int*)(ws + off_tail);
    float* invl2 = (float*)(ws + off_invl2);
    float* C = (float*)(ws + off_C);

    pobs_kernel<<<BATCH, 256, 0, stream>>>(mask, invp);
    pad_kernel<<<(BATCH * NH * 32) / 256, 256, 0, stream>>>(G);
    gram_kernel<<<dim3(49, BATCH), 256, 0, stream>>>(x, mask, G);
    jacobi_kernel<<<BATCH, 1024, 0, stream>>>(G);
    select_kernel<<<BATCH, 256, 0, stream>>>(G, tail, invl2);
    ctail_kernel<<<dim3(6, BATCH), 128, 0, stream>>>(G, x, mask, tail, invl2, C);
    out_kernel<<<dim3(7, 7, BATCH), 256, 0, stream>>>(G, x, mask, tail, C, invp, out);
}